// Round 4
// baseline (5323.823 us; speedup 1.0000x reference)
//
#include <hip/hip_runtime.h>
#include <cstdint>

// ---------------- problem constants ----------------
#define TT 512
#define BB 64
#define DD 1024
#define HH 1024
#define NWG 128          // persistent workgroups; each owns 8 hidden units (32 gate cols)

typedef __attribute__((ext_vector_type(8))) __bf16 bf16x8;
typedef __attribute__((ext_vector_type(4))) float f32x4;

// ---- workspace layout (bytes) ----
#define WS_XQ    0
#define WS_WHB   67108864ULL
#define WS_HQ    83886080ULL
#define WS_FLAGS 151126016ULL
// flags: 32 aggregated epoch sub-counters (kqh x act-wave x producer-group-of-8),
// one 128B line each. Monotone: each producer atomicAdds +1 per step, never
// cleared. Counter value after H[t] fully published = 8*(t+1).
#define FLAGS_BYTES (32 * 128)

__device__ __forceinline__ unsigned short f2bf(float f) {
    unsigned int u = __float_as_uint(f);
    u = (u + 0x7fffu + ((u >> 16) & 1u)) >> 16;
    return (unsigned short)u;
}

__device__ __forceinline__ float sigm(float x) {
    return 1.0f / (1.0f + __expf(-x));
}
__device__ __forceinline__ float tanh_f(float x) {
    float a = fabsf(x);
    float e = __expf(-2.0f * a);
    float t = (1.0f - e) / (1.0f + e);
    return copysignf(t, x);
}

__device__ __forceinline__ unsigned long long pack4bf(float a, float b, float c, float d) {
    return (unsigned long long)f2bf(a)
         | ((unsigned long long)f2bf(b) << 16)
         | ((unsigned long long)f2bf(c) << 32)
         | ((unsigned long long)f2bf(d) << 48);
}

// ---------------- kernel 1: convert X fp32 -> bf16 ----------------
__global__ void cvt_x(const float* __restrict__ X, unsigned short* __restrict__ Xq) {
    int i = blockIdx.x * blockDim.x + threadIdx.x;   // one thread per 8 elems
    const int n8 = TT * BB * DD / 8;
    if (i >= n8) return;
    const float4* s = (const float4*)X;
    float4 a = s[2 * i], b = s[2 * i + 1];
    union { unsigned short u[8]; uint4 q; } r;
    r.u[0] = f2bf(a.x); r.u[1] = f2bf(a.y); r.u[2] = f2bf(a.z); r.u[3] = f2bf(a.w);
    r.u[4] = f2bf(b.x); r.u[5] = f2bf(b.y); r.u[6] = f2bf(b.z); r.u[7] = f2bf(b.w);
    ((uint4*)Xq)[i] = r.q;
}

// ---------------- kernel 2: pack [Wx;Wh] into per-wave B-register order ----------------
// Linear element order: ((((wg*4 + kq)*16 + s)*2 + ct)*64 + lane)*8 + m
// lane holds B[k_global = kq*512 + s*32 + (lane>>4)*8 + m][col = ct*16 + (lane&15)]
// col j (0..31): gate = j>>3 (i,f,o,c), h = wg*8 + (j&7). k<1024 -> Wx row k, else Wh row k-1024.
__global__ void pack_w(const float* __restrict__ Wxi, const float* __restrict__ Wxf,
                       const float* __restrict__ Wxo, const float* __restrict__ Wxc,
                       const float* __restrict__ Whi, const float* __restrict__ Whf,
                       const float* __restrict__ Who, const float* __restrict__ Whc,
                       unsigned short* __restrict__ WhB) {
    int tid = blockIdx.x * blockDim.x + threadIdx.x;      // 0 .. 1,048,575 (one per 8 elems)
    int lane = tid & 63;
    int ct   = (tid >> 6) & 1;
    int s    = (tid >> 7) & 15;
    int kq   = (tid >> 11) & 3;
    int wg   = tid >> 13;
    int col  = ct * 16 + (lane & 15);
    int gate = col >> 3;
    int h    = wg * 8 + (col & 7);
    int kb   = kq * 512 + s * 32 + ((lane >> 4) & 3) * 8;   // k of element m=0

    const float* Wx[4] = {Wxi, Wxf, Wxo, Wxc};
    const float* Wh[4] = {Whi, Whf, Who, Whc};
    const float* W = (kb < 1024) ? (Wx[gate] + (size_t)kb * HH + h)
                                 : (Wh[gate] + (size_t)(kb - 1024) * HH + h);
    union { unsigned short u[8]; uint4 q; } r;
#pragma unroll
    for (int m = 0; m < 8; ++m) r.u[m] = f2bf(W[(size_t)m * HH]);
    *(uint4*)(WhB + (size_t)tid * 8) = r.q;
}

// ---------------- kernel 3: persistent LSTM recurrence ----------------
// 128 WGs x 512 threads (8 waves). Waves 0-3: X part (kq 0,1 x rhalf).
// Waves 4-7: H part (kq 2,3 x rhalf). Waves 4,5 also run activation+stores
// (wave 4 = rows 0-31 = act-slice a=0, wave 5 = rows 32-63 = a=1).
//
// SYNC DESIGN:
//   * Hq data: relaxed AGENT-scope stores (coherent at LLC). Fresh address
//     per step; consumers PLAIN-load it (L2-cacheable) only after the
//     matching counters are seen.
//   * flags are AGGREGATED EPOCH SUB-COUNTERS: one 128B line per
//     (kqh, act-wave a, producer-group g of 8). Producer (wg, a) does ONE
//     relaxed AGENT atomicAdd(+1) after its Hq stores are LLC-acked.
//     Consumer (kqh, rhalf) polls 8 lines with 8 LANES (not 64) until
//     counter >= 8*(t+1). This cuts the grid-wide poll request rate 8x —
//     round 3 showed the poll storm itself (512 waves x 64-line gathers)
//     was queueing ahead of producer stores at the LLC.
//   * group g covers hidden cols g*64..+64 = exactly one 128B Hq line span,
//     so no Hq line is plain-loaded before ALL its owners published (same
//     stale-L2 safety argument as the per-producer-flag design).
//   * producer: data stores -> wave s_waitcnt vmcnt(0) (LLC ack) ->
//     lane0 counter add -> THEN fp32 out stores (off the critical path).
__global__ void __launch_bounds__(512, 2)
lstm_seq(const unsigned short* __restrict__ Xq, const unsigned short* __restrict__ WhB,
         unsigned short* __restrict__ Hq, int* flags,
         const float* __restrict__ H0, const float* __restrict__ C0,
         const float* __restrict__ bi, const float* __restrict__ bfp,
         const float* __restrict__ bo, const float* __restrict__ bc,
         float* __restrict__ out) {
    __shared__ float gpart[4][64][36];   // pad 36: MFMA-epilogue writes 2-way = free

    const int wg    = blockIdx.x;
    const int tid   = threadIdx.x;
    const int wv    = tid >> 6;
    const int lane  = tid & 63;
    const int quad  = lane >> 4;
    const int l15   = lane & 15;
    const int rhalf = wv & 1;
    const bool isH  = (wv >= 4);
    const int kq    = isH ? 2 + ((wv - 4) >> 1) : (wv >> 1);   // global K-quarter 0..3
    const int arow0 = rhalf * 32 + l15;      // GEMM A row for rt=0 (rt=1 adds 16)

    // activation identity: waves 4,5 -> one (row r2, 4-col group) per thread
    const bool isAct = (wv == 4) || (wv == 5);
    const int aidx   = tid - 256;            // 0..127 for act threads
    const int r2     = aidx >> 1;            // batch row 0..63 (wave4: 0-31, wave5: 32-63)
    const int ahalf  = aidx & 1;             // which 4-col half of the 8 h-cols
    const int hcol0  = wg * 8 + ahalf * 4;

    float Bi[4], Bf[4], Bo[4], Bc[4], Cr[4];
    if (isAct) {
#pragma unroll
        for (int j = 0; j < 4; ++j) {
            Bi[j] = bi[hcol0 + j];
            Bf[j] = bfp[hcol0 + j];
            Bo[j] = bo[hcol0 + j];
            Bc[j] = bc[hcol0 + j];
            Cr[j] = C0[(size_t)r2 * HH + hcol0 + j];
        }
    }

    // ---- preload this wave's 32 B-fragments (AGPR/VGPR unified file) ----
    bf16x8 Breg[16][2];
    {
        const unsigned short* wp = WhB + (size_t)(wg * 4 + kq) * (16 * 2 * 64 * 8);
#pragma unroll
        for (int s = 0; s < 16; ++s)
#pragma unroll
            for (int ct = 0; ct < 2; ++ct)
                Breg[s][ct] = *(const bf16x8*)(wp + ((s * 2 + ct) * 64 + lane) * 8);
    }

    // this producer's sub-counter line index (per act-slice a): ((kqh_of_wg*2 + a)*8 + g)
    const int my_kqh  = wg >> 6;
    const int my_grp  = (wg >> 3) & 7;

    // ---- publish Hq[0] slice, drain, bump both act-slice counters ----
    if (tid < 64) {
        const float* s = H0 + (size_t)tid * HH + wg * 8;
        unsigned long long a = pack4bf(s[0], s[1], s[2], s[3]);
        unsigned long long b = pack4bf(s[4], s[5], s[6], s[7]);
        unsigned long long* d = (unsigned long long*)(Hq + (size_t)tid * HH + wg * 8);
        __hip_atomic_store(d,     a, __ATOMIC_RELAXED, __HIP_MEMORY_SCOPE_AGENT);
        __hip_atomic_store(d + 1, b, __ATOMIC_RELAXED, __HIP_MEMORY_SCOPE_AGENT);
    }
    if (wv == 0) {
        asm volatile("s_waitcnt vmcnt(0)" ::: "memory");   // Hq[0] + Breg acked
        if (lane < 2)   // a = lane: counter line ((my_kqh*2 + a)*8 + my_grp)
            __hip_atomic_fetch_add(flags + (((my_kqh * 2 + lane) * 8) + my_grp) * 32, 1,
                                   __ATOMIC_RELAXED, __HIP_MEMORY_SCOPE_AGENT);
    }

    for (int t = 0; t < TT; ++t) {
        f32x4 a00 = {0.f,0.f,0.f,0.f}, a01 = {0.f,0.f,0.f,0.f};
        f32x4 a10 = {0.f,0.f,0.f,0.f}, a11 = {0.f,0.f,0.f,0.f};

        if (!isH) {
            // ---- X part: no cross-WG dependency ----
            const unsigned short* xb = Xq + ((size_t)(t * BB + arow0)) * DD + kq * 512 + quad * 8;
#pragma unroll
            for (int s = 0; s < 16; ++s) {
                bf16x8 af0 = *(const bf16x8*)(xb + s * 32);
                bf16x8 af1 = *(const bf16x8*)(xb + 16 * DD + s * 32);
                a00 = __builtin_amdgcn_mfma_f32_16x16x32_bf16(af0, Breg[s][0], a00, 0, 0, 0);
                a01 = __builtin_amdgcn_mfma_f32_16x16x32_bf16(af0, Breg[s][1], a01, 0, 0, 0);
                a10 = __builtin_amdgcn_mfma_f32_16x16x32_bf16(af1, Breg[s][0], a10, 0, 0, 0);
                a11 = __builtin_amdgcn_mfma_f32_16x16x32_bf16(af1, Breg[s][1], a11, 0, 0, 0);
            }
        } else {
            // ---- H part: poll 8 aggregated sub-counters with 8 lanes ----
            // group g (lane<8) covers producers kqh*64 + g*8..+8 = hidden
            // cols (kqh*64+g*8)*8..  s-group s uses producers s*4..s*4+3 of
            // this quadrant -> phase 0 (s=0..7) needs groups 0..3, phase 1
            // needs all 8.
            const int kqh = kq - 2;
            const int thr = 8 * (t + 1);
            const int* fp = flags + (((kqh * 2 + rhalf) * 8) + lane) * 32;   // lane<8 only
            const unsigned short* hb = Hq + ((size_t)(t * BB + arow0)) * HH + kqh * 512 + quad * 8;

            int myf = (lane < 8)
                ? __hip_atomic_load(fp, __ATOMIC_RELAXED, __HIP_MEMORY_SCOPE_AGENT) : 0;
            unsigned long long got = __ballot(lane < 8 && myf >= thr);
            while ((got & 0xFull) != 0xFull) {
                __builtin_amdgcn_s_sleep(1);
                if (lane < 8 && myf < thr)
                    myf = __hip_atomic_load(fp, __ATOMIC_RELAXED, __HIP_MEMORY_SCOPE_AGENT);
                got = __ballot(lane < 8 && myf >= thr);
            }
            asm volatile("" ::: "memory");   // no Hq loads above the counter wait
            {
                bf16x8 af[8][2];
#pragma unroll
                for (int s = 0; s < 8; ++s) {
                    af[s][0] = *(const bf16x8*)(hb + s * 32);
                    af[s][1] = *(const bf16x8*)(hb + 16 * HH + s * 32);
                }
#pragma unroll
                for (int s = 0; s < 8; ++s) {
                    a00 = __builtin_amdgcn_mfma_f32_16x16x32_bf16(af[s][0], Breg[s][0], a00, 0, 0, 0);
                    a01 = __builtin_amdgcn_mfma_f32_16x16x32_bf16(af[s][0], Breg[s][1], a01, 0, 0, 0);
                    a10 = __builtin_amdgcn_mfma_f32_16x16x32_bf16(af[s][1], Breg[s][0], a10, 0, 0, 0);
                    a11 = __builtin_amdgcn_mfma_f32_16x16x32_bf16(af[s][1], Breg[s][1], a11, 0, 0, 0);
                }
            }

            while ((got & 0xFFull) != 0xFFull) {
                __builtin_amdgcn_s_sleep(1);
                if (lane < 8 && myf < thr)
                    myf = __hip_atomic_load(fp, __ATOMIC_RELAXED, __HIP_MEMORY_SCOPE_AGENT);
                got = __ballot(lane < 8 && myf >= thr);
            }
            asm volatile("" ::: "memory");
            {
                bf16x8 af[8][2];
#pragma unroll
                for (int s = 0; s < 8; ++s) {
                    af[s][0] = *(const bf16x8*)(hb + (8 + s) * 32);
                    af[s][1] = *(const bf16x8*)(hb + 16 * HH + (8 + s) * 32);
                }
#pragma unroll
                for (int s = 0; s < 8; ++s) {
                    a00 = __builtin_amdgcn_mfma_f32_16x16x32_bf16(af[s][0], Breg[8 + s][0], a00, 0, 0, 0);
                    a01 = __builtin_amdgcn_mfma_f32_16x16x32_bf16(af[s][0], Breg[8 + s][1], a01, 0, 0, 0);
                    a10 = __builtin_amdgcn_mfma_f32_16x16x32_bf16(af[s][1], Breg[8 + s][0], a10, 0, 0, 0);
                    a11 = __builtin_amdgcn_mfma_f32_16x16x32_bf16(af[s][1], Breg[8 + s][1], a11, 0, 0, 0);
                }
            }
        }

        // ---- C-frag (col=l15, row=quad*4+r) -> LDS partials ----
#pragma unroll
        for (int r = 0; r < 4; ++r) {
            int row0 = rhalf * 32 + quad * 4 + r;
            gpart[kq][row0][l15]           = a00[r];
            gpart[kq][row0][16 + l15]      = a01[r];
            gpart[kq][row0 + 16][l15]      = a10[r];
            gpart[kq][row0 + 16][16 + l15] = a11[r];
        }
        __syncthreads();   // A(t): all 4 kq partials visible

        // ---- activation + stores, 128 threads, direct from registers ----
        if (isAct) {
            float hv[4];
#pragma unroll
            for (int j = 0; j < 4; ++j) {
                const int c = ahalf * 4 + j;
                float gi = gpart[0][r2][c]      + gpart[1][r2][c]
                         + gpart[2][r2][c]      + gpart[3][r2][c]      + Bi[j];
                float gf = gpart[0][r2][8 + c]  + gpart[1][r2][8 + c]
                         + gpart[2][r2][8 + c]  + gpart[3][r2][8 + c]  + Bf[j];
                float go = gpart[0][r2][16 + c] + gpart[1][r2][16 + c]
                         + gpart[2][r2][16 + c] + gpart[3][r2][16 + c] + Bo[j];
                float gc = gpart[0][r2][24 + c] + gpart[1][r2][24 + c]
                         + gpart[2][r2][24 + c] + gpart[3][r2][24 + c] + Bc[j];
                float I = sigm(gi), F = sigm(gf), O = sigm(go), G = tanh_f(gc);
                Cr[j] = F * Cr[j] + I * G;
                hv[j] = O * tanh_f(Cr[j]);
            }
            // publish Hq[t+1], wave-drain to LLC, bump counter, then out
            unsigned long long pk = pack4bf(hv[0], hv[1], hv[2], hv[3]);
            __hip_atomic_store(
                (unsigned long long*)(Hq + ((size_t)(t + 1) * BB + r2) * HH + hcol0),
                pk, __ATOMIC_RELAXED, __HIP_MEMORY_SCOPE_AGENT);
            asm volatile("s_waitcnt vmcnt(0)" ::: "memory");   // all 64 lanes' Hq stores acked
            if (lane == 0)   // counter line ((my_kqh*2 + a)*8 + my_grp), a = wv-4
                __hip_atomic_fetch_add(
                    flags + (((my_kqh * 2 + (wv - 4)) * 8) + my_grp) * 32, 1,
                    __ATOMIC_RELAXED, __HIP_MEMORY_SCOPE_AGENT);
            // fp32 out stores (ack entirely off the critical path)
            float4 v = make_float4(hv[0], hv[1], hv[2], hv[3]);
            *(float4*)(out + ((size_t)t * BB + r2) * HH + hcol0) = v;
            if (t == TT - 1) {   // H_f copy
                *(float4*)(out + (size_t)TT * BB * HH + (size_t)r2 * HH + hcol0) = v;
            }
        }
        __syncthreads();   // B(t): gpart reusable next step
    }

    // ---- C_f ----
    if (isAct) {
        float* cf = out + (size_t)TT * BB * HH + (size_t)BB * HH;
        *(float4*)(cf + (size_t)r2 * HH + hcol0) = make_float4(Cr[0], Cr[1], Cr[2], Cr[3]);
    }
}

// ---------------- launch ----------------
extern "C" void kernel_launch(void* const* d_in, const int* in_sizes, int n_in,
                              void* d_out, int out_size, void* d_ws, size_t ws_size,
                              hipStream_t stream) {
    const float* X   = (const float*)d_in[0];
    const float* H0  = (const float*)d_in[1];
    const float* C0  = (const float*)d_in[2];
    const float* Wxi = (const float*)d_in[3];
    const float* Wxf = (const float*)d_in[4];
    const float* Wxo = (const float*)d_in[5];
    const float* Wxc = (const float*)d_in[6];
    const float* Whi = (const float*)d_in[7];
    const float* Whf = (const float*)d_in[8];
    const float* Who = (const float*)d_in[9];
    const float* Whc = (const float*)d_in[10];
    const float* bi  = (const float*)d_in[11];
    const float* bf_ = (const float*)d_in[12];
    const float* bo  = (const float*)d_in[13];
    const float* bc  = (const float*)d_in[14];

    char* ws = (char*)d_ws;
    unsigned short* Xq  = (unsigned short*)(ws + WS_XQ);
    unsigned short* WhB = (unsigned short*)(ws + WS_WHB);
    unsigned short* Hq  = (unsigned short*)(ws + WS_HQ);
    int* flags          = (int*)(ws + WS_FLAGS);

    hipMemsetAsync(flags, 0, FLAGS_BYTES, stream);

    hipLaunchKernelGGL(cvt_x, dim3(TT * BB * DD / 8 / 256), dim3(256), 0, stream, X, Xq);
    hipLaunchKernelGGL(pack_w, dim3(4096), dim3(256), 0, stream,
                       Wxi, Wxf, Wxo, Wxc, Whi, Whf, Who, Whc, WhB);
    hipLaunchKernelGGL(lstm_seq, dim3(NWG), dim3(512), 0, stream,
                       Xq, WhB, Hq, flags, H0, C0, bi, bf_, bo, bc, (float*)d_out);
}

// Round 6
// 4539.352 us; speedup vs baseline: 1.1728x; 1.1728x over previous
//
#include <hip/hip_runtime.h>
#include <cstdint>

// ---------------- problem constants ----------------
#define TT 512
#define BB 64
#define DD 1024
#define HH 1024
#define NWG 128          // persistent workgroups; each owns 8 hidden units (32 gate cols)

typedef __attribute__((ext_vector_type(8))) __bf16 bf16x8;
typedef __attribute__((ext_vector_type(4))) float f32x4;

// ---- workspace layout (bytes) ----
#define WS_XQ    0
#define WS_WHB   67108864ULL
#define WS_HQ2   83886080ULL
#define WS_FLAGS 151126016ULL
// Hq2 block layout: block (t, wg, a) = 512B contiguous at
//   ((t*NWG + wg)*2 + a)*512.  word w (8B) = row a*32 + (w>>1),
//   cols wg*8 + (w&1)*4 .. +4 (4 x bf16).
#define HQ2_BYTES ((size_t)(TT + 1) * NWG * 2 * 512)   // 67,239,936
// flags: one 128B line per (producer wg, act-wave a); 8 rotating 16B
// step-slots per line, value = step+1 (monotone, never cleared).
#define FLAGS_BYTES (256 * 128)

__device__ __forceinline__ unsigned short f2bf(float f) {
    unsigned int u = __float_as_uint(f);
    u = (u + 0x7fffu + ((u >> 16) & 1u)) >> 16;
    return (unsigned short)u;
}

__device__ __forceinline__ float sigm(float x) {
    return 1.0f / (1.0f + __expf(-x));
}
__device__ __forceinline__ float tanh_f(float x) {
    float a = fabsf(x);
    float e = __expf(-2.0f * a);
    float t = (1.0f - e) / (1.0f + e);
    return copysignf(t, x);
}

__device__ __forceinline__ unsigned long long pack4bf(float a, float b, float c, float d) {
    return (unsigned long long)f2bf(a)
         | ((unsigned long long)f2bf(b) << 16)
         | ((unsigned long long)f2bf(c) << 32)
         | ((unsigned long long)f2bf(d) << 48);
}

// ---------------- kernel 1: convert X fp32 -> bf16 ----------------
__global__ void cvt_x(const float* __restrict__ X, unsigned short* __restrict__ Xq) {
    int i = blockIdx.x * blockDim.x + threadIdx.x;   // one thread per 8 elems
    const int n8 = TT * BB * DD / 8;
    if (i >= n8) return;
    const float4* s = (const float4*)X;
    float4 a = s[2 * i], b = s[2 * i + 1];
    union { unsigned short u[8]; uint4 q; } r;
    r.u[0] = f2bf(a.x); r.u[1] = f2bf(a.y); r.u[2] = f2bf(a.z); r.u[3] = f2bf(a.w);
    r.u[4] = f2bf(b.x); r.u[5] = f2bf(b.y); r.u[6] = f2bf(b.z); r.u[7] = f2bf(b.w);
    ((uint4*)Xq)[i] = r.q;
}

// ---------------- kernel 2: pack [Wx;Wh] into per-wave B-register order ----------------
// Linear element order: ((((wg*4 + kq)*16 + s)*2 + ct)*64 + lane)*8 + m
// lane holds B[k_global = kq*512 + s*32 + (lane>>4)*8 + m][col = ct*16 + (lane&15)]
// col j (0..31): gate = j>>3 (i,f,o,c), h = wg*8 + (j&7). k<1024 -> Wx row k, else Wh row k-1024.
__global__ void pack_w(const float* __restrict__ Wxi, const float* __restrict__ Wxf,
                       const float* __restrict__ Wxo, const float* __restrict__ Wxc,
                       const float* __restrict__ Whi, const float* __restrict__ Whf,
                       const float* __restrict__ Who, const float* __restrict__ Whc,
                       unsigned short* __restrict__ WhB) {
    int tid = blockIdx.x * blockDim.x + threadIdx.x;      // 0 .. 1,048,575 (one per 8 elems)
    int lane = tid & 63;
    int ct   = (tid >> 6) & 1;
    int s    = (tid >> 7) & 15;
    int kq   = (tid >> 11) & 3;
    int wg   = tid >> 13;
    int col  = ct * 16 + (lane & 15);
    int gate = col >> 3;
    int h    = wg * 8 + (col & 7);
    int kb   = kq * 512 + s * 32 + ((lane >> 4) & 3) * 8;   // k of element m=0

    const float* Wx[4] = {Wxi, Wxf, Wxo, Wxc};
    const float* Wh[4] = {Whi, Whf, Who, Whc};
    const float* W = (kb < 1024) ? (Wx[gate] + (size_t)kb * HH + h)
                                 : (Wh[gate] + (size_t)(kb - 1024) * HH + h);
    union { unsigned short u[8]; uint4 q; } r;
#pragma unroll
    for (int m = 0; m < 8; ++m) r.u[m] = f2bf(W[(size_t)m * HH]);
    *(uint4*)(WhB + (size_t)tid * 8) = r.q;
}

// ---------------- kernel 3: persistent LSTM recurrence ----------------
// 128 WGs x 512 threads (8 waves). Waves 0-3: X part (kq 0,1 x rhalf).
// Waves 4-7: H part (kq 2,3 x rhalf). Waves 4,5 also run activation+stores
// (wave 4 = rows 0-31 = act-slice a=0, wave 5 = rows 32-63 = a=1).
//
// SYNC DESIGN (round-3 semantics, improved layout/schedule):
//   * Hq2 data: relaxed AGENT-scope stores into ONE contiguous 512B block
//     per (producer, act-wave) -> 4-line ack burst instead of 32 scattered
//     lines. Fresh address each step; consumers PLAIN-load (L2-cacheable)
//     only after the matching flag is seen, and no one else ever wrote the
//     address -> no stale-L2 window (same argument as rounds 0-4).
//   * flags: one 128B line per (wg, a), 8 rotating slots, monotone value
//     t+1. Producer: data stores -> s_waitcnt vmcnt(0) (LLC ack) -> lane0
//     flag store -> THEN fp32 out stores (off the critical path).
//   * consumer: 16 MICRO-GATES — s-group s needs only producers
//     s*4..s*4+3 (ballot bits 0xF<<(4s)); its MFMAs issue as soon as those
//     4 landed, stragglers hide under earlier MFMAs.
//   * ONE barrier per step: gpart is parity-double-buffered, so X waves
//     run step t+1's GEMM while act waves do activation+publish of t.
__global__ void __launch_bounds__(512, 2)
lstm_seq(const unsigned short* __restrict__ Xq, const unsigned short* __restrict__ WhB,
         unsigned char* __restrict__ Hq2, int* flags,
         const float* __restrict__ H0, const float* __restrict__ C0,
         const float* __restrict__ bi, const float* __restrict__ bfp,
         const float* __restrict__ bo, const float* __restrict__ bc,
         float* __restrict__ out) {
    __shared__ float gpart[2][4][64][36];   // parity-double-buffered partials

    const int wg    = blockIdx.x;
    const int tid   = threadIdx.x;
    const int wv    = tid >> 6;
    const int lane  = tid & 63;
    const int quad  = lane >> 4;
    const int l15   = lane & 15;
    const int rhalf = wv & 1;
    const bool isH  = (wv >= 4);
    const int kq    = isH ? 2 + ((wv - 4) >> 1) : (wv >> 1);   // global K-quarter 0..3
    const int arow0 = rhalf * 32 + l15;      // X-GEMM A row for rt=0 (rt=1 adds 16)

    // activation identity: waves 4,5 -> one (row r2, 4-col group) per thread
    const bool isAct = (wv == 4) || (wv == 5);
    const int aidx   = tid - 256;            // 0..127 for act threads
    const int r2     = aidx >> 1;            // batch row 0..63 (wave4: 0-31, wave5: 32-63)
    const int ahalf  = aidx & 1;             // which 4-col half of the 8 h-cols
    const int hcol0  = wg * 8 + ahalf * 4;

    float Bi[4], Bf[4], Bo[4], Bc[4], Cr[4];
    if (isAct) {
#pragma unroll
        for (int j = 0; j < 4; ++j) {
            Bi[j] = bi[hcol0 + j];
            Bf[j] = bfp[hcol0 + j];
            Bo[j] = bo[hcol0 + j];
            Bc[j] = bc[hcol0 + j];
            Cr[j] = C0[(size_t)r2 * HH + hcol0 + j];
        }
    }

    // ---- preload this wave's 32 B-fragments (AGPR/VGPR unified file) ----
    bf16x8 Breg[16][2];
    {
        const unsigned short* wp = WhB + (size_t)(wg * 4 + kq) * (16 * 2 * 64 * 8);
#pragma unroll
        for (int s = 0; s < 16; ++s)
#pragma unroll
            for (int ct = 0; ct < 2; ++ct)
                Breg[s][ct] = *(const bf16x8*)(wp + ((s * 2 + ct) * 64 + lane) * 8);
    }

    // ---- publish H0 blocks (wave 0 does both a=0,1), drain, set flags ----
    if (wv == 0) {
#pragma unroll
        for (int a = 0; a < 2; ++a) {
            int row = a * 32 + (lane >> 1);
            const float* s = H0 + (size_t)row * HH + wg * 8 + (lane & 1) * 4;
            unsigned long long v = pack4bf(s[0], s[1], s[2], s[3]);
            unsigned long long* d =
                (unsigned long long*)(Hq2 + (((size_t)wg) * 2 + a) * 512) + lane;
            __hip_atomic_store(d, v, __ATOMIC_RELAXED, __HIP_MEMORY_SCOPE_AGENT);
        }
        asm volatile("s_waitcnt vmcnt(0)" ::: "memory");   // H0 blocks acked at LLC
        if (lane < 2)   // flag lines (wg, a=lane), slot 0, value 1
            __hip_atomic_store(flags + ((wg * 2 + lane) * 8 + 0) * 4, 1,
                               __ATOMIC_RELAXED, __HIP_MEMORY_SCOPE_AGENT);
    }

    for (int t = 0; t < TT; ++t) {
        const int pb = t & 1;
        f32x4 a00 = {0.f,0.f,0.f,0.f}, a01 = {0.f,0.f,0.f,0.f};
        f32x4 a10 = {0.f,0.f,0.f,0.f}, a11 = {0.f,0.f,0.f,0.f};

        if (!isH) {
            // ---- X part: no cross-WG dependency; overlaps act/publish of t-1 ----
            const unsigned short* xb = Xq + ((size_t)(t * BB + arow0)) * DD + kq * 512 + quad * 8;
#pragma unroll
            for (int s = 0; s < 16; ++s) {
                bf16x8 af0 = *(const bf16x8*)(xb + s * 32);
                bf16x8 af1 = *(const bf16x8*)(xb + 16 * DD + s * 32);
                a00 = __builtin_amdgcn_mfma_f32_16x16x32_bf16(af0, Breg[s][0], a00, 0, 0, 0);
                a01 = __builtin_amdgcn_mfma_f32_16x16x32_bf16(af0, Breg[s][1], a01, 0, 0, 0);
                a10 = __builtin_amdgcn_mfma_f32_16x16x32_bf16(af1, Breg[s][0], a10, 0, 0, 0);
                a11 = __builtin_amdgcn_mfma_f32_16x16x32_bf16(af1, Breg[s][1], a11, 0, 0, 0);
            }
        } else {
            // ---- H part: per-producer flag poll + 16 micro-gates ----
            // lane polls producer p = kqh*64 + lane, act-slice a = rhalf.
            // s-group s reads blocks p = kqh*64 + s*4 + quad -> needs
            // ballot bits s*4..s*4+3 only.
            const int kqh  = kq - 2;
            const int slot = t & 7;
            const int thr  = t + 1;
            const int* fp  = flags + (((kqh * 64 + lane) * 2 + rhalf) * 8 + slot) * 4;
            const unsigned char* tb =
                Hq2 + (((size_t)t * NWG + kqh * 64) * 2 + rhalf) * 512;

            int myf = __hip_atomic_load(fp, __ATOMIC_RELAXED, __HIP_MEMORY_SCOPE_AGENT);
            unsigned long long got = __ballot(myf >= thr);
#pragma unroll
            for (int s = 0; s < 16; ++s) {
                const unsigned long long need = 0xFull << (s * 4);
                while ((got & need) != need) {
                    __builtin_amdgcn_s_sleep(1);
                    if (myf < thr)
                        myf = __hip_atomic_load(fp, __ATOMIC_RELAXED, __HIP_MEMORY_SCOPE_AGENT);
                    got = __ballot(myf >= thr);
                }
                asm volatile("" ::: "memory");   // no data loads above the gate
                const unsigned char* bb = tb + (size_t)(s * 4 + quad) * 1024;
                bf16x8 af0 = *(const bf16x8*)(bb + l15 * 16);          // row l15
                bf16x8 af1 = *(const bf16x8*)(bb + (l15 + 16) * 16);   // row l15+16
                a00 = __builtin_amdgcn_mfma_f32_16x16x32_bf16(af0, Breg[s][0], a00, 0, 0, 0);
                a01 = __builtin_amdgcn_mfma_f32_16x16x32_bf16(af0, Breg[s][1], a01, 0, 0, 0);
                a10 = __builtin_amdgcn_mfma_f32_16x16x32_bf16(af1, Breg[s][0], a10, 0, 0, 0);
                a11 = __builtin_amdgcn_mfma_f32_16x16x32_bf16(af1, Breg[s][1], a11, 0, 0, 0);
            }
        }

        // ---- C-frag (col=l15, row=quad*4+r) -> LDS partials (parity buffer) ----
#pragma unroll
        for (int r = 0; r < 4; ++r) {
            int row0 = rhalf * 32 + quad * 4 + r;
            gpart[pb][kq][row0][l15]           = a00[r];
            gpart[pb][kq][row0][16 + l15]      = a01[r];
            gpart[pb][kq][row0 + 16][l15]      = a10[r];
            gpart[pb][kq][row0 + 16][16 + l15] = a11[r];
        }
        __syncthreads();   // the ONE barrier: all 4 kq partials of step t visible

        // ---- activation + publish, 128 threads, direct from registers.
        //      X waves already proceed to step t+1 (other gpart parity). ----
        if (isAct) {
            float hv[4];
#pragma unroll
            for (int j = 0; j < 4; ++j) {
                const int c = ahalf * 4 + j;
                float gi = gpart[pb][0][r2][c]      + gpart[pb][1][r2][c]
                         + gpart[pb][2][r2][c]      + gpart[pb][3][r2][c]      + Bi[j];
                float gf = gpart[pb][0][r2][8 + c]  + gpart[pb][1][r2][8 + c]
                         + gpart[pb][2][r2][8 + c]  + gpart[pb][3][r2][8 + c]  + Bf[j];
                float go = gpart[pb][0][r2][16 + c] + gpart[pb][1][r2][16 + c]
                         + gpart[pb][2][r2][16 + c] + gpart[pb][3][r2][16 + c] + Bo[j];
                float gc = gpart[pb][0][r2][24 + c] + gpart[pb][1][r2][24 + c]
                         + gpart[pb][2][r2][24 + c] + gpart[pb][3][r2][24 + c] + Bc[j];
                float I = sigm(gi), F = sigm(gf), O = sigm(go), G = tanh_f(gc);
                Cr[j] = F * Cr[j] + I * G;
                hv[j] = O * tanh_f(Cr[j]);
            }
            // publish block (t+1, wg, a): word w = lane, one 512B burst;
            // vmcnt(0) -> LLC-acked; lane0 sets the flag; then out stores.
            const int a = wv - 4;
            const int w = aidx & 63;   // == lane
            unsigned long long pk = pack4bf(hv[0], hv[1], hv[2], hv[3]);
            unsigned long long* d = (unsigned long long*)
                (Hq2 + (((size_t)(t + 1) * NWG + wg) * 2 + a) * 512) + w;
            __hip_atomic_store(d, pk, __ATOMIC_RELAXED, __HIP_MEMORY_SCOPE_AGENT);
            asm volatile("s_waitcnt vmcnt(0)" ::: "memory");   // 512B burst acked at LLC
            if (lane == 0)   // flag line (wg, a), slot (t+1)&7, value t+2
                __hip_atomic_store(
                    flags + ((wg * 2 + a) * 8 + ((t + 1) & 7)) * 4, t + 2,
                    __ATOMIC_RELAXED, __HIP_MEMORY_SCOPE_AGENT);
            // fp32 out stores (ack entirely off the critical path)
            float4 v = make_float4(hv[0], hv[1], hv[2], hv[3]);
            *(float4*)(out + ((size_t)t * BB + r2) * HH + hcol0) = v;
            if (t == TT - 1) {   // H_f copy
                *(float4*)(out + (size_t)TT * BB * HH + (size_t)r2 * HH + hcol0) = v;
            }
        }
        // no second barrier: gpart is parity-double-buffered
    }

    // ---- C_f ----
    if (isAct) {
        float* cf = out + (size_t)TT * BB * HH + (size_t)BB * HH;
        *(float4*)(cf + (size_t)r2 * HH + hcol0) = make_float4(Cr[0], Cr[1], Cr[2], Cr[3]);
    }
}

// ---------------- launch ----------------
extern "C" void kernel_launch(void* const* d_in, const int* in_sizes, int n_in,
                              void* d_out, int out_size, void* d_ws, size_t ws_size,
                              hipStream_t stream) {
    const float* X   = (const float*)d_in[0];
    const float* H0  = (const float*)d_in[1];
    const float* C0  = (const float*)d_in[2];
    const float* Wxi = (const float*)d_in[3];
    const float* Wxf = (const float*)d_in[4];
    const float* Wxo = (const float*)d_in[5];
    const float* Wxc = (const float*)d_in[6];
    const float* Whi = (const float*)d_in[7];
    const float* Whf = (const float*)d_in[8];
    const float* Who = (const float*)d_in[9];
    const float* Whc = (const float*)d_in[10];
    const float* bi  = (const float*)d_in[11];
    const float* bf_ = (const float*)d_in[12];
    const float* bo  = (const float*)d_in[13];
    const float* bc  = (const float*)d_in[14];

    char* ws = (char*)d_ws;
    unsigned short* Xq  = (unsigned short*)(ws + WS_XQ);
    unsigned short* WhB = (unsigned short*)(ws + WS_WHB);
    unsigned char*  Hq2 = (unsigned char*)(ws + WS_HQ2);
    int* flags          = (int*)(ws + WS_FLAGS);

    hipMemsetAsync(flags, 0, FLAGS_BYTES, stream);

    hipLaunchKernelGGL(cvt_x, dim3(TT * BB * DD / 8 / 256), dim3(256), 0, stream, X, Xq);
    hipLaunchKernelGGL(pack_w, dim3(4096), dim3(256), 0, stream,
                       Wxi, Wxf, Wxo, Wxc, Whi, Whf, Who, Whc, WhB);
    hipLaunchKernelGGL(lstm_seq, dim3(NWG), dim3(512), 0, stream,
                       Xq, WhB, Hq2, flags, H0, C0, bi, bf_, bo, bc, (float*)d_out);
}